// Round 3
// baseline (745.570 us; speedup 1.0000x reference)
//
#include <hip/hip_runtime.h>
#include <hip/hip_bf16.h>
#include <math.h>

#define BATCH 4
#define SEQ   2048
#define DM    1024
#define NH    16
#define DH    64

typedef __bf16 bf16x8 __attribute__((ext_vector_type(8)));
typedef float  f32x4  __attribute__((ext_vector_type(4)));

// Load 8 consecutive fp32 elements at element-index idx, convert to bf16x8.
__device__ __forceinline__ bf16x8 load8f(const float* __restrict__ base, size_t idx) {
    const float4 a = *(const float4*)(base + idx);
    const float4 b = *(const float4*)(base + idx + 4);
    bf16x8 r;
    r[0] = (__bf16)a.x; r[1] = (__bf16)a.y; r[2] = (__bf16)a.z; r[3] = (__bf16)a.w;
    r[4] = (__bf16)b.x; r[5] = (__bf16)b.y; r[6] = (__bf16)b.z; r[7] = (__bf16)b.w;
    return r;
}

// ---------------------------------------------------------------------------
// Kernel 1: K,V projection. grid=(128 row tiles, 16 heads, 2 {k,v}),
// block=256. C[64x64] = X[64x1024] @ W_h[1024x64]. Out layout [B,H,S,D] bf16.
// ---------------------------------------------------------------------------
__global__ __launch_bounds__(256)
void kv_kernel(const float* __restrict__ X,
               const float* __restrict__ Wk,
               const float* __restrict__ Wv,
               __bf16* __restrict__ Ko,
               __bf16* __restrict__ Vo)
{
    const int rowTile = blockIdx.x;           // 0..127
    const int h       = blockIdx.y;           // 0..15
    const int c       = blockIdx.z;           // 0..1
    const float* W    = (c == 0 ? Wk : Wv) + (size_t)h * DM * DH;
    __bf16* Out       = (c == 0 ? Ko : Vo);

    __shared__ __align__(16) __bf16 As[64 * 40];  // 64x32 A tile, stride 40
    __shared__ __align__(16) __bf16 Bt[64 * 40];  // B^T: Bt[n][k]

    const int t    = threadIdx.x;
    const int wave = t >> 6;
    const int lane = t & 63;
    const int l15  = lane & 15;
    const int quad = lane >> 4;

    f32x4 acc[4];
#pragma unroll
    for (int i = 0; i < 4; ++i) acc[i] = (f32x4){0.f, 0.f, 0.f, 0.f};

    const int r0    = rowTile * 64;
    const int a_row = t >> 2;            // 0..63
    const int a_col = (t & 3) * 8;       // 0,8,16,24
    const int b_row = t >> 3;            // 0..31 (k)
    const int b_col = (t & 7) * 8;       // 0..56 (n)

    for (int k0 = 0; k0 < DM; k0 += 32) {
        __syncthreads();
        *(bf16x8*)&As[a_row * 40 + a_col] =
            load8f(X, (size_t)(r0 + a_row) * DM + k0 + a_col);
        {
            bf16x8 tv = load8f(W, (size_t)(k0 + b_row) * DH + b_col);
#pragma unroll
            for (int j = 0; j < 8; ++j)
                Bt[(b_col + j) * 40 + b_row] = tv[j];
        }
        __syncthreads();

        bf16x8 a = *(const bf16x8*)&As[(wave * 16 + l15) * 40 + quad * 8];
#pragma unroll
        for (int ct = 0; ct < 4; ++ct) {
            bf16x8 b = *(const bf16x8*)&Bt[(ct * 16 + l15) * 40 + quad * 8];
            acc[ct] = __builtin_amdgcn_mfma_f32_16x16x32_bf16(a, b, acc[ct], 0, 0, 0);
        }
    }

#pragma unroll
    for (int ct = 0; ct < 4; ++ct) {
#pragma unroll
        for (int reg = 0; reg < 4; ++reg) {
            int r = r0 + wave * 16 + quad * 4 + reg;
            int b = r >> 11;            // / SEQ
            int s = r & (SEQ - 1);
            int d = ct * 16 + l15;
            Out[(((size_t)(b * NH + h)) * SEQ + s) * DH + d] = (__bf16)acc[ct][reg];
        }
    }
}

// ---------------------------------------------------------------------------
// Kernel 2: fused Q-projection + causal flash attention.
// grid=(32 q-tiles, B*H=64), block=256. Phase 1: Q tile (pre-scaled 1/8)
// from X @ Wq_h.  Phase 2: online-softmax flash attention over K,V.
// Writes concat [B, S, H*D] bf16.
// ---------------------------------------------------------------------------
__global__ __launch_bounds__(256)
void attn_kernel(const float* __restrict__ X,
                 const float* __restrict__ Wq,
                 const __bf16* __restrict__ K,
                 const __bf16* __restrict__ V,
                 __bf16* __restrict__ Cat)
{
    const int qt = blockIdx.x;      // 0..31
    const int bh = blockIdx.y;      // 0..63
    const int b  = bh >> 4;
    const int h  = bh & 15;

    const __bf16* Kg = K + (size_t)bh * SEQ * DH;
    const __bf16* Vg = V + (size_t)bh * SEQ * DH;
    const float*  Wqh = Wq + (size_t)h * DM * DH;

    __shared__ __align__(16) __bf16 Qs[64 * 72];
    __shared__ __align__(16) __bf16 Ks[64 * 72];   // doubles as X staging
    __shared__ __align__(16) __bf16 Vt[64 * 72];   // doubles as Wq^T staging
    __shared__ __align__(16) __bf16 Ps[64 * 72];

    const int t    = threadIdx.x;
    const int wave = t >> 6;
    const int lane = t & 63;
    const int l15  = lane & 15;
    const int quad = lane >> 4;

    const int q0 = qt * 64;

    // ---- Phase 1: Q tile ----
    {
        const int a_row = t >> 2;        // 0..63
        const int a_col = (t & 3) * 8;   // 0..24
        const int b_row = t >> 3;        // 0..31
        const int b_col = (t & 7) * 8;   // 0..56
        f32x4 qacc[4];
#pragma unroll
        for (int i = 0; i < 4; ++i) qacc[i] = (f32x4){0.f, 0.f, 0.f, 0.f};

        for (int k0 = 0; k0 < DM; k0 += 32) {
            __syncthreads();
            *(bf16x8*)&Ks[a_row * 72 + a_col] =
                load8f(X, (size_t)(b * SEQ + q0 + a_row) * DM + k0 + a_col);
            {
                bf16x8 tv = load8f(Wqh, (size_t)(k0 + b_row) * DH + b_col);
#pragma unroll
                for (int j = 0; j < 8; ++j)
                    Vt[(b_col + j) * 72 + b_row] = tv[j];
            }
            __syncthreads();

            bf16x8 a = *(const bf16x8*)&Ks[(wave * 16 + l15) * 72 + quad * 8];
#pragma unroll
            for (int ct = 0; ct < 4; ++ct) {
                bf16x8 bb = *(const bf16x8*)&Vt[(ct * 16 + l15) * 72 + quad * 8];
                qacc[ct] = __builtin_amdgcn_mfma_f32_16x16x32_bf16(a, bb, qacc[ct], 0, 0, 0);
            }
        }
        // Q tile -> LDS (C-layout positions), pre-scaled by 1/sqrt(64)
#pragma unroll
        for (int ct = 0; ct < 4; ++ct)
#pragma unroll
            for (int r = 0; r < 4; ++r)
                Qs[(wave * 16 + quad * 4 + r) * 72 + ct * 16 + l15] =
                    (__bf16)(qacc[ct][r] * 0.125f);
    }

    // ---- Phase 2: flash attention ----
    float m_i[4], l_i[4];
    f32x4 o[4];
#pragma unroll
    for (int r = 0; r < 4; ++r) { m_i[r] = -INFINITY; l_i[r] = 0.f; }
#pragma unroll
    for (int ct = 0; ct < 4; ++ct) o[ct] = (f32x4){0.f, 0.f, 0.f, 0.f};

    for (int kt = 0; kt <= qt; ++kt) {
        const int kv0 = kt * 64;
        __syncthreads();
#pragma unroll
        for (int i = 0; i < 2; ++i) {
            int flat = i * 2048 + t * 8;
            int row = flat >> 6, col = flat & 63;
            *(bf16x8*)&Ks[row * 72 + col] =
                *(const bf16x8*)&Kg[(size_t)(kv0 + row) * DH + col];
            bf16x8 tv = *(const bf16x8*)&Vg[(size_t)(kv0 + row) * DH + col];
#pragma unroll
            for (int j = 0; j < 8; ++j)
                Vt[(col + j) * 72 + row] = tv[j];
        }
        __syncthreads();

        // S = Q K^T  (Q pre-scaled)
        f32x4 sc[4];
#pragma unroll
        for (int ct = 0; ct < 4; ++ct) sc[ct] = (f32x4){0.f, 0.f, 0.f, 0.f};
#pragma unroll
        for (int ks = 0; ks < 2; ++ks) {
            bf16x8 a = *(const bf16x8*)&Qs[(wave * 16 + l15) * 72 + ks * 32 + quad * 8];
#pragma unroll
            for (int ct = 0; ct < 4; ++ct) {
                bf16x8 bb = *(const bf16x8*)&Ks[(ct * 16 + l15) * 72 + ks * 32 + quad * 8];
                sc[ct] = __builtin_amdgcn_mfma_f32_16x16x32_bf16(a, bb, sc[ct], 0, 0, 0);
            }
        }

        // causal mask (diagonal tile only)
        if (kt == qt) {
#pragma unroll
            for (int ct = 0; ct < 4; ++ct) {
#pragma unroll
                for (int r = 0; r < 4; ++r) {
                    int qrow = wave * 16 + quad * 4 + r;
                    int kcol = ct * 16 + l15;
                    if (kcol > qrow) sc[ct][r] = -INFINITY;
                }
            }
        }

        // online softmax (row = quad*4+r; 16 lanes sharing quad hold its cols)
#pragma unroll
        for (int r = 0; r < 4; ++r) {
            float mx = fmaxf(fmaxf(sc[0][r], sc[1][r]), fmaxf(sc[2][r], sc[3][r]));
#pragma unroll
            for (int off = 1; off < 16; off <<= 1)
                mx = fmaxf(mx, __shfl_xor(mx, off, 64));
            float mnew = fmaxf(m_i[r], mx);
            float alpha = __expf(m_i[r] - mnew);
            float ps = 0.f;
#pragma unroll
            for (int ct = 0; ct < 4; ++ct) {
                float p = __expf(sc[ct][r] - mnew);
                sc[ct][r] = p;
                ps += p;
            }
#pragma unroll
            for (int off = 1; off < 16; off <<= 1)
                ps += __shfl_xor(ps, off, 64);
            l_i[r] = l_i[r] * alpha + ps;
            m_i[r] = mnew;
#pragma unroll
            for (int ct = 0; ct < 4; ++ct) o[ct][r] *= alpha;
        }

        // P: C-layout -> LDS (wave-private rows)
#pragma unroll
        for (int ct = 0; ct < 4; ++ct)
#pragma unroll
            for (int r = 0; r < 4; ++r)
                Ps[(wave * 16 + quad * 4 + r) * 72 + ct * 16 + l15] = (__bf16)sc[ct][r];
        __syncthreads();

        // O += P @ V
#pragma unroll
        for (int ks = 0; ks < 2; ++ks) {
            bf16x8 a = *(const bf16x8*)&Ps[(wave * 16 + l15) * 72 + ks * 32 + quad * 8];
#pragma unroll
            for (int ct = 0; ct < 4; ++ct) {
                bf16x8 bb = *(const bf16x8*)&Vt[(ct * 16 + l15) * 72 + ks * 32 + quad * 8];
                o[ct] = __builtin_amdgcn_mfma_f32_16x16x32_bf16(a, bb, o[ct], 0, 0, 0);
            }
        }
    }

    // epilogue: normalize, write concat[b][s][h*64+d]
#pragma unroll
    for (int ct = 0; ct < 4; ++ct) {
#pragma unroll
        for (int r = 0; r < 4; ++r) {
            int row = wave * 16 + quad * 4 + r;
            int s   = q0 + row;
            float val = o[ct][r] / l_i[r];
            Cat[((size_t)(b * SEQ + s)) * DM + h * DH + ct * 16 + l15] = (__bf16)val;
        }
    }
}

// ---------------------------------------------------------------------------
// Kernel 3: output projection. grid=(128,16), block=256.
// out[8192x1024] = Cat[8192x1024] @ Wout[1024x1024], FP32 out.
// ---------------------------------------------------------------------------
__global__ __launch_bounds__(256)
void oproj_kernel(const __bf16* __restrict__ A,
                  const float* __restrict__ W,
                  float* __restrict__ C)
{
    const int rowTile = blockIdx.x;  // 0..127
    const int colTile = blockIdx.y;  // 0..15
    const int n0 = colTile * 64;

    __shared__ __align__(16) __bf16 As[64 * 40];
    __shared__ __align__(16) __bf16 Bt[64 * 40];

    const int t    = threadIdx.x;
    const int wave = t >> 6;
    const int lane = t & 63;
    const int l15  = lane & 15;
    const int quad = lane >> 4;

    f32x4 acc[4];
#pragma unroll
    for (int i = 0; i < 4; ++i) acc[i] = (f32x4){0.f, 0.f, 0.f, 0.f};

    const int r0    = rowTile * 64;
    const int a_row = t >> 2;
    const int a_col = (t & 3) * 8;
    const int b_row = t >> 3;        // k 0..31
    const int b_col = (t & 7) * 8;   // n 0..56

    for (int k0 = 0; k0 < DM; k0 += 32) {
        __syncthreads();
        *(bf16x8*)&As[a_row * 40 + a_col] =
            *(const bf16x8*)&A[(size_t)(r0 + a_row) * DM + k0 + a_col];
        {
            bf16x8 tv = load8f(W, (size_t)(k0 + b_row) * DM + n0 + b_col);
#pragma unroll
            for (int j = 0; j < 8; ++j)
                Bt[(b_col + j) * 40 + b_row] = tv[j];
        }
        __syncthreads();

        bf16x8 a = *(const bf16x8*)&As[(wave * 16 + l15) * 40 + quad * 8];
#pragma unroll
        for (int ct = 0; ct < 4; ++ct) {
            bf16x8 b = *(const bf16x8*)&Bt[(ct * 16 + l15) * 40 + quad * 8];
            acc[ct] = __builtin_amdgcn_mfma_f32_16x16x32_bf16(a, b, acc[ct], 0, 0, 0);
        }
    }

#pragma unroll
    for (int ct = 0; ct < 4; ++ct) {
#pragma unroll
        for (int reg = 0; reg < 4; ++reg) {
            int r = r0 + wave * 16 + quad * 4 + reg;
            int n = n0 + ct * 16 + l15;
            C[(size_t)r * DM + n] = acc[ct][reg];
        }
    }
}

// ---------------------------------------------------------------------------
extern "C" void kernel_launch(void* const* d_in, const int* in_sizes, int n_in,
                              void* d_out, int out_size, void* d_ws, size_t ws_size,
                              hipStream_t stream)
{
    (void)in_sizes; (void)n_in; (void)out_size; (void)ws_size;
    const float* X  = (const float*)d_in[0];
    const float* Wq = (const float*)d_in[1];
    const float* Wk = (const float*)d_in[2];
    const float* Wv = (const float*)d_in[3];
    const float* Wo = (const float*)d_in[4];
    float* out = (float*)d_out;

    char* ws = (char*)d_ws;
    const size_t buf_bytes = (size_t)BATCH * NH * SEQ * DH * sizeof(__bf16); // 16 MiB
    __bf16* Kb   = (__bf16*)(ws);
    __bf16* Vb   = (__bf16*)(ws + buf_bytes);
    __bf16* Cat  = (__bf16*)(ws + 2 * buf_bytes);

    kv_kernel<<<dim3(128, 16, 2), 256, 0, stream>>>(X, Wk, Wv, Kb, Vb);
    attn_kernel<<<dim3(32, 64), 256, 0, stream>>>(X, Wq, Kb, Vb, Cat);
    oproj_kernel<<<dim3(128, 16), 256, 0, stream>>>(Cat, Wo, out);
}

// Round 4
// 454.716 us; speedup vs baseline: 1.6396x; 1.6396x over previous
//
#include <hip/hip_runtime.h>
#include <hip/hip_bf16.h>
#include <math.h>

#define BATCH 4
#define SEQ   2048
#define DM    1024
#define NH    16
#define DH    64

typedef __bf16 bf16x8 __attribute__((ext_vector_type(8)));
typedef __bf16 bf16x4 __attribute__((ext_vector_type(4)));
typedef float  f32x4  __attribute__((ext_vector_type(4)));

// Load 8 consecutive fp32 elements, convert to bf16x8 (RNE).
__device__ __forceinline__ bf16x8 load8f(const float* __restrict__ base, size_t idx) {
    const float4 a = *(const float4*)(base + idx);
    const float4 b = *(const float4*)(base + idx + 4);
    bf16x8 r;
    r[0] = (__bf16)a.x; r[1] = (__bf16)a.y; r[2] = (__bf16)a.z; r[3] = (__bf16)a.w;
    r[4] = (__bf16)b.x; r[5] = (__bf16)b.y; r[6] = (__bf16)b.z; r[7] = (__bf16)b.w;
    return r;
}

// ---------------------------------------------------------------------------
// Kernel 0: weight transpose  src[K][N] fp32 -> dst[N][K] bf16.
// grid=(K/64, N/64, nmat); block=256.
// ---------------------------------------------------------------------------
__global__ __launch_bounds__(256)
void wtrans_kernel(const float* __restrict__ src, __bf16* __restrict__ dst,
                   int K, int N)
{
    const int k0 = blockIdx.x * 64;
    const int n0 = blockIdx.y * 64;
    src += (size_t)blockIdx.z * K * N;
    dst += (size_t)blockIdx.z * K * N;

    __shared__ __bf16 T[64][65];
    const int t = threadIdx.x;

#pragma unroll
    for (int i = 0; i < 4; ++i) {
        int row = i * 16 + (t >> 4);      // k within tile
        int col = (t & 15) * 4;           // n within tile
        float4 v = *(const float4*)&src[(size_t)(k0 + row) * N + n0 + col];
        T[col + 0][row] = (__bf16)v.x;
        T[col + 1][row] = (__bf16)v.y;
        T[col + 2][row] = (__bf16)v.z;
        T[col + 3][row] = (__bf16)v.w;
    }
    __syncthreads();
#pragma unroll
    for (int i = 0; i < 4; ++i) {
        int n  = i * 16 + (t >> 4);
        int kc = (t & 15) * 4;
        bf16x4 v;
        v[0] = T[n][kc + 0]; v[1] = T[n][kc + 1];
        v[2] = T[n][kc + 2]; v[3] = T[n][kc + 3];
        *(bf16x4*)&dst[(size_t)(n0 + n) * K + k0 + kc] = v;
    }
}

// ---------------------------------------------------------------------------
// Kernel 1: fused QKV projection. grid=(128 row tiles, 16 heads), block=256.
// Stages X tile once, reuses for Q/K/V (12 MFMA per 2 barriers).
// Q (pre-scaled 1/8) and K -> [B,H,S,D]; V -> transposed [B,H,D,S]. All bf16.
// ---------------------------------------------------------------------------
__global__ __launch_bounds__(256)
void qkv_kernel(const float* __restrict__ X,
                const __bf16* __restrict__ Wqt,   // [h][64][1024] bf16 (n-major)
                const __bf16* __restrict__ Wkt,
                const __bf16* __restrict__ Wvt,
                __bf16* __restrict__ Qo,
                __bf16* __restrict__ Ko,
                __bf16* __restrict__ Vto)
{
    const int rowTile = blockIdx.x;           // 0..127
    const int h       = blockIdx.y;           // 0..15
    const size_t woff = (size_t)h * DH * DM;

    __shared__ __align__(16) __bf16 As [64 * 40];
    __shared__ __align__(16) __bf16 Bq [64 * 40];
    __shared__ __align__(16) __bf16 Bk [64 * 40];
    __shared__ __align__(16) __bf16 Bv [64 * 40];

    const int t    = threadIdx.x;
    const int wave = t >> 6;
    const int lane = t & 63;
    const int l15  = lane & 15;
    const int quad = lane >> 4;

    f32x4 aq[4], ak[4], av[4];
#pragma unroll
    for (int i = 0; i < 4; ++i) {
        aq[i] = (f32x4){0.f, 0.f, 0.f, 0.f};
        ak[i] = (f32x4){0.f, 0.f, 0.f, 0.f};
        av[i] = (f32x4){0.f, 0.f, 0.f, 0.f};
    }

    const int r0    = rowTile * 64;
    const int a_row = t >> 2;            // 0..63
    const int a_col = (t & 3) * 8;       // 0,8,16,24
    const int b_row = t >> 2;            // 0..63 (n = d)
    const int b_col = (t & 3) * 8;       // 0..24 (k)

    for (int k0 = 0; k0 < DM; k0 += 32) {
        __syncthreads();
        *(bf16x8*)&As[a_row * 40 + a_col] =
            load8f(X, (size_t)(r0 + a_row) * DM + k0 + a_col);
        *(bf16x8*)&Bq[b_row * 40 + b_col] =
            *(const bf16x8*)&Wqt[woff + (size_t)b_row * DM + k0 + b_col];
        *(bf16x8*)&Bk[b_row * 40 + b_col] =
            *(const bf16x8*)&Wkt[woff + (size_t)b_row * DM + k0 + b_col];
        *(bf16x8*)&Bv[b_row * 40 + b_col] =
            *(const bf16x8*)&Wvt[woff + (size_t)b_row * DM + k0 + b_col];
        __syncthreads();

        bf16x8 a = *(const bf16x8*)&As[(wave * 16 + l15) * 40 + quad * 8];
#pragma unroll
        for (int ct = 0; ct < 4; ++ct) {
            bf16x8 bq = *(const bf16x8*)&Bq[(ct * 16 + l15) * 40 + quad * 8];
            aq[ct] = __builtin_amdgcn_mfma_f32_16x16x32_bf16(a, bq, aq[ct], 0, 0, 0);
            bf16x8 bk = *(const bf16x8*)&Bk[(ct * 16 + l15) * 40 + quad * 8];
            ak[ct] = __builtin_amdgcn_mfma_f32_16x16x32_bf16(a, bk, ak[ct], 0, 0, 0);
            bf16x8 bv = *(const bf16x8*)&Bv[(ct * 16 + l15) * 40 + quad * 8];
            av[ct] = __builtin_amdgcn_mfma_f32_16x16x32_bf16(a, bv, av[ct], 0, 0, 0);
        }
    }

    // epilogue: rows r = r0 + wave*16 + quad*4 + reg (4 consecutive), col d
    {
        const int rbase = r0 + wave * 16 + quad * 4;
        const int b = rbase >> 11;
        const int s = rbase & (SEQ - 1);
        const size_t bh = (size_t)(b * NH + h);
#pragma unroll
        for (int ct = 0; ct < 4; ++ct) {
            const int d = ct * 16 + l15;
            // Q (scaled), K: [B,H,S,D]
#pragma unroll
            for (int reg = 0; reg < 4; ++reg) {
                Qo[(bh * SEQ + s + reg) * DH + d] = (__bf16)(aq[ct][reg] * 0.125f);
                Ko[(bh * SEQ + s + reg) * DH + d] = (__bf16)ak[ct][reg];
            }
            // V^T: [B,H,D,S] — 4 consecutive s pack into one 8B store
            bf16x4 vv;
            vv[0] = (__bf16)av[ct][0]; vv[1] = (__bf16)av[ct][1];
            vv[2] = (__bf16)av[ct][2]; vv[3] = (__bf16)av[ct][3];
            *(bf16x4*)&Vto[(bh * DH + d) * SEQ + s] = vv;
        }
    }
}

// ---------------------------------------------------------------------------
// Kernel 2: causal flash attention (Q precomputed & pre-scaled).
// grid=(32 q-tiles, B*H=64), block=256. Writes concat [B, S, H*D] bf16.
// Row-sum of P rides a ones-column MFMA (no sum butterfly; l == o_l).
// ---------------------------------------------------------------------------
__global__ __launch_bounds__(256)
void attn_kernel(const __bf16* __restrict__ Q,
                 const __bf16* __restrict__ K,
                 const __bf16* __restrict__ Vt,
                 __bf16* __restrict__ Cat)
{
    const int qt = 31 - blockIdx.x;   // heavy blocks first
    const int bh = blockIdx.y;        // 0..63
    const int b  = bh >> 4;
    const int h  = bh & 15;

    const __bf16* Qg  = Q  + (size_t)bh * SEQ * DH;
    const __bf16* Kg  = K  + (size_t)bh * SEQ * DH;
    const __bf16* Vtg = Vt + (size_t)bh * DH * SEQ;

    __shared__ __align__(16) __bf16 Qs[64 * 72];
    __shared__ __align__(16) __bf16 Ks[64 * 72];
    __shared__ __align__(16) __bf16 Vs[64 * 72];   // V^T tile: [d][kv]
    __shared__ __align__(16) __bf16 Ps[64 * 72];

    const int t    = threadIdx.x;
    const int wave = t >> 6;
    const int lane = t & 63;
    const int l15  = lane & 15;
    const int quad = lane >> 4;

    const int q0 = qt * 64;

    // stage Q tile (pure b128 copy; pre-scaled at projection)
#pragma unroll
    for (int i = 0; i < 2; ++i) {
        int flat = i * 2048 + t * 8;
        int row = flat >> 6, col = flat & 63;
        *(bf16x8*)&Qs[row * 72 + col] =
            *(const bf16x8*)&Qg[(size_t)(q0 + row) * DH + col];
    }

    bf16x8 ones;
#pragma unroll
    for (int j = 0; j < 8; ++j) ones[j] = (__bf16)1.0f;

    float m_i[4];
    f32x4 o[4], ol;
#pragma unroll
    for (int r = 0; r < 4; ++r) m_i[r] = -INFINITY;
#pragma unroll
    for (int ct = 0; ct < 4; ++ct) o[ct] = (f32x4){0.f, 0.f, 0.f, 0.f};
    ol = (f32x4){0.f, 0.f, 0.f, 0.f};

    for (int kt = 0; kt <= qt; ++kt) {
        const int kv0 = kt * 64;
        __syncthreads();   // prior readers of Ks/Vs drained (also covers Qs once)
#pragma unroll
        for (int i = 0; i < 2; ++i) {
            int flat = i * 2048 + t * 8;
            int row = flat >> 6, col = flat & 63;
            *(bf16x8*)&Ks[row * 72 + col] =
                *(const bf16x8*)&Kg[(size_t)(kv0 + row) * DH + col];
            *(bf16x8*)&Vs[row * 72 + col] =
                *(const bf16x8*)&Vtg[(size_t)row * SEQ + kv0 + col];
        }
        __syncthreads();

        // S = Q K^T
        f32x4 sc[4];
#pragma unroll
        for (int ct = 0; ct < 4; ++ct) sc[ct] = (f32x4){0.f, 0.f, 0.f, 0.f};
#pragma unroll
        for (int ks = 0; ks < 2; ++ks) {
            bf16x8 a = *(const bf16x8*)&Qs[(wave * 16 + l15) * 72 + ks * 32 + quad * 8];
#pragma unroll
            for (int ct = 0; ct < 4; ++ct) {
                bf16x8 bb = *(const bf16x8*)&Ks[(ct * 16 + l15) * 72 + ks * 32 + quad * 8];
                sc[ct] = __builtin_amdgcn_mfma_f32_16x16x32_bf16(a, bb, sc[ct], 0, 0, 0);
            }
        }

        if (kt == qt) {     // causal mask, diagonal tile only
#pragma unroll
            for (int ct = 0; ct < 4; ++ct)
#pragma unroll
                for (int r = 0; r < 4; ++r) {
                    int qrow = wave * 16 + quad * 4 + r;
                    int kcol = ct * 16 + l15;
                    if (kcol > qrow) sc[ct][r] = -INFINITY;
                }
        }

        // online max + exp; row sum deferred to ones-MFMA
#pragma unroll
        for (int r = 0; r < 4; ++r) {
            float mx = fmaxf(fmaxf(sc[0][r], sc[1][r]), fmaxf(sc[2][r], sc[3][r]));
#pragma unroll
            for (int off = 1; off < 16; off <<= 1)
                mx = fmaxf(mx, __shfl_xor(mx, off, 64));
            float mnew  = fmaxf(m_i[r], mx);
            float alpha = __expf(m_i[r] - mnew);
            m_i[r] = mnew;
#pragma unroll
            for (int ct = 0; ct < 4; ++ct) {
                sc[ct][r] = __expf(sc[ct][r] - mnew);
                o[ct][r] *= alpha;
            }
            ol[r] *= alpha;
        }

        // P: C-layout -> LDS (wave-private rows; no barrier needed)
#pragma unroll
        for (int ct = 0; ct < 4; ++ct)
#pragma unroll
            for (int r = 0; r < 4; ++r)
                Ps[(wave * 16 + quad * 4 + r) * 72 + ct * 16 + l15] = (__bf16)sc[ct][r];

        // O += P @ V ; ol += P @ 1
#pragma unroll
        for (int ks = 0; ks < 2; ++ks) {
            bf16x8 a = *(const bf16x8*)&Ps[(wave * 16 + l15) * 72 + ks * 32 + quad * 8];
#pragma unroll
            for (int ct = 0; ct < 4; ++ct) {
                bf16x8 bb = *(const bf16x8*)&Vs[(ct * 16 + l15) * 72 + ks * 32 + quad * 8];
                o[ct] = __builtin_amdgcn_mfma_f32_16x16x32_bf16(a, bb, o[ct], 0, 0, 0);
            }
            ol = __builtin_amdgcn_mfma_f32_16x16x32_bf16(a, ones, ol, 0, 0, 0);
        }
    }

    // epilogue: normalize, write concat[b][s][h*64+d]
#pragma unroll
    for (int ct = 0; ct < 4; ++ct)
#pragma unroll
        for (int r = 0; r < 4; ++r) {
            int row = wave * 16 + quad * 4 + r;
            int s   = q0 + row;
            float val = o[ct][r] / ol[r];
            Cat[((size_t)(b * SEQ + s)) * DM + h * DH + ct * 16 + l15] = (__bf16)val;
        }
}

// ---------------------------------------------------------------------------
// Kernel 3: output projection. grid=(128,16), block=256.
// out[8192x1024] = Cat[8192x1024](bf16) @ Wout[1024x1024], fp32 out.
// Wout staged from pre-transposed Wot[n][k] bf16.
// ---------------------------------------------------------------------------
__global__ __launch_bounds__(256)
void oproj_kernel(const __bf16* __restrict__ A,
                  const __bf16* __restrict__ Wot,
                  float* __restrict__ C)
{
    const int rowTile = blockIdx.x;  // 0..127
    const int colTile = blockIdx.y;  // 0..15
    const int n0 = colTile * 64;

    __shared__ __align__(16) __bf16 As[64 * 40];
    __shared__ __align__(16) __bf16 Bt[64 * 40];

    const int t    = threadIdx.x;
    const int wave = t >> 6;
    const int lane = t & 63;
    const int l15  = lane & 15;
    const int quad = lane >> 4;

    f32x4 acc[4];
#pragma unroll
    for (int i = 0; i < 4; ++i) acc[i] = (f32x4){0.f, 0.f, 0.f, 0.f};

    const int r0    = rowTile * 64;
    const int a_row = t >> 2;
    const int a_col = (t & 3) * 8;

    for (int k0 = 0; k0 < DM; k0 += 32) {
        __syncthreads();
        *(bf16x8*)&As[a_row * 40 + a_col] =
            *(const bf16x8*)&A[(size_t)(r0 + a_row) * DM + k0 + a_col];
        *(bf16x8*)&Bt[a_row * 40 + a_col] =
            *(const bf16x8*)&Wot[(size_t)(n0 + a_row) * DM + k0 + a_col];
        __syncthreads();

        bf16x8 a = *(const bf16x8*)&As[(wave * 16 + l15) * 40 + quad * 8];
#pragma unroll
        for (int ct = 0; ct < 4; ++ct) {
            bf16x8 b = *(const bf16x8*)&Bt[(ct * 16 + l15) * 40 + quad * 8];
            acc[ct] = __builtin_amdgcn_mfma_f32_16x16x32_bf16(a, b, acc[ct], 0, 0, 0);
        }
    }

#pragma unroll
    for (int ct = 0; ct < 4; ++ct)
#pragma unroll
        for (int reg = 0; reg < 4; ++reg) {
            int r = r0 + wave * 16 + quad * 4 + reg;
            int n = n0 + ct * 16 + l15;
            C[(size_t)r * DM + n] = acc[ct][reg];
        }
}

// ---------------------------------------------------------------------------
extern "C" void kernel_launch(void* const* d_in, const int* in_sizes, int n_in,
                              void* d_out, int out_size, void* d_ws, size_t ws_size,
                              hipStream_t stream)
{
    (void)in_sizes; (void)n_in; (void)out_size; (void)ws_size;
    const float* X  = (const float*)d_in[0];
    const float* Wq = (const float*)d_in[1];
    const float* Wk = (const float*)d_in[2];
    const float* Wv = (const float*)d_in[3];
    const float* Wo = (const float*)d_in[4];
    float* out = (float*)d_out;

    char* ws = (char*)d_ws;
    const size_t wqkv_b = (size_t)NH * DM * DH * sizeof(__bf16);          // 2 MiB
    const size_t wo_b   = (size_t)DM * DM * sizeof(__bf16);               // 2 MiB
    const size_t big_b  = (size_t)BATCH * NH * SEQ * DH * sizeof(__bf16); // 16 MiB
    __bf16* Wqt = (__bf16*)(ws);
    __bf16* Wkt = (__bf16*)(ws + wqkv_b);
    __bf16* Wvt = (__bf16*)(ws + 2 * wqkv_b);
    __bf16* Wot = (__bf16*)(ws + 3 * wqkv_b);
    __bf16* Qb  = (__bf16*)(ws + 3 * wqkv_b + wo_b);
    __bf16* Kb  = (__bf16*)(ws + 3 * wqkv_b + wo_b + big_b);
    __bf16* Vtb = (__bf16*)(ws + 3 * wqkv_b + wo_b + 2 * big_b);
    __bf16* Cat = (__bf16*)(ws + 3 * wqkv_b + wo_b + 3 * big_b);

    wtrans_kernel<<<dim3(16, 1, 16), 256, 0, stream>>>(Wq, Wqt, DM, DH);
    wtrans_kernel<<<dim3(16, 1, 16), 256, 0, stream>>>(Wk, Wkt, DM, DH);
    wtrans_kernel<<<dim3(16, 1, 16), 256, 0, stream>>>(Wv, Wvt, DM, DH);
    wtrans_kernel<<<dim3(16, 16, 1), 256, 0, stream>>>(Wo, Wot, DM, DM);
    qkv_kernel<<<dim3(128, 16), 256, 0, stream>>>(X, Wqt, Wkt, Wvt, Qb, Kb, Vtb);
    attn_kernel<<<dim3(32, 64), 256, 0, stream>>>(Qb, Kb, Vtb, Cat);
    oproj_kernel<<<dim3(128, 16), 256, 0, stream>>>(Cat, Wot, out);
}

// Round 5
// 440.293 us; speedup vs baseline: 1.6933x; 1.0328x over previous
//
#include <hip/hip_runtime.h>
#include <hip/hip_bf16.h>
#include <math.h>

#define BATCH 4
#define SEQ   2048
#define DM    1024
#define NH    16
#define DH    64

// log2(e) / sqrt(DH)
#define QSCALE 0.1803368801111204f

typedef __bf16 bf16x8 __attribute__((ext_vector_type(8)));
typedef __bf16 bf16x4 __attribute__((ext_vector_type(4)));
typedef float  f32x4  __attribute__((ext_vector_type(4)));

// Load 8 consecutive fp32 elements, convert to bf16x8 (RNE).
__device__ __forceinline__ bf16x8 load8f(const float* __restrict__ base, size_t idx) {
    const float4 a = *(const float4*)(base + idx);
    const float4 b = *(const float4*)(base + idx + 4);
    bf16x8 r;
    r[0] = (__bf16)a.x; r[1] = (__bf16)a.y; r[2] = (__bf16)a.z; r[3] = (__bf16)a.w;
    r[4] = (__bf16)b.x; r[5] = (__bf16)b.y; r[6] = (__bf16)b.z; r[7] = (__bf16)b.w;
    return r;
}

// ---------------------------------------------------------------------------
// Kernel 0: weight transpose  src[K][N] fp32 -> dst[N][K] bf16.
// ---------------------------------------------------------------------------
__global__ __launch_bounds__(256)
void wtrans_kernel(const float* __restrict__ src, __bf16* __restrict__ dst,
                   int K, int N)
{
    const int k0 = blockIdx.x * 64;
    const int n0 = blockIdx.y * 64;
    src += (size_t)blockIdx.z * K * N;
    dst += (size_t)blockIdx.z * K * N;

    __shared__ __bf16 T[64][65];
    const int t = threadIdx.x;

#pragma unroll
    for (int i = 0; i < 4; ++i) {
        int row = i * 16 + (t >> 4);
        int col = (t & 15) * 4;
        float4 v = *(const float4*)&src[(size_t)(k0 + row) * N + n0 + col];
        T[col + 0][row] = (__bf16)v.x;
        T[col + 1][row] = (__bf16)v.y;
        T[col + 2][row] = (__bf16)v.z;
        T[col + 3][row] = (__bf16)v.w;
    }
    __syncthreads();
#pragma unroll
    for (int i = 0; i < 4; ++i) {
        int n  = i * 16 + (t >> 4);
        int kc = (t & 15) * 4;
        bf16x4 v;
        v[0] = T[n][kc + 0]; v[1] = T[n][kc + 1];
        v[2] = T[n][kc + 2]; v[3] = T[n][kc + 3];
        *(bf16x4*)&dst[(size_t)(n0 + n) * K + k0 + kc] = v;
    }
}

// ---------------------------------------------------------------------------
// Kernel 1: fused QKV projection. grid=(64 row tiles of 128, 16 heads).
// 2 row-strips per wave; 24 MFMA per barrier-pair. Q pre-scaled by QSCALE.
// Q,K -> [B,H,S,D]; V -> transposed [B,H,D,S]. All bf16.
// ---------------------------------------------------------------------------
__global__ __launch_bounds__(256)
void qkv_kernel(const float* __restrict__ X,
                const __bf16* __restrict__ Wqt,   // [h][64][1024] (d-major)
                const __bf16* __restrict__ Wkt,
                const __bf16* __restrict__ Wvt,
                __bf16* __restrict__ Qo,
                __bf16* __restrict__ Ko,
                __bf16* __restrict__ Vto)
{
    const int rowTile = blockIdx.x;           // 0..63
    const int h       = blockIdx.y;           // 0..15
    const size_t woff = (size_t)h * DH * DM;

    __shared__ __align__(16) __bf16 As[128 * 40];   // 128 rows x 32 k
    __shared__ __align__(16) __bf16 Bq[64 * 40];
    __shared__ __align__(16) __bf16 Bk[64 * 40];
    __shared__ __align__(16) __bf16 Bv[64 * 40];

    const int t    = threadIdx.x;
    const int wave = t >> 6;
    const int lane = t & 63;
    const int l15  = lane & 15;
    const int quad = lane >> 4;

    f32x4 aq[2][4], ak[2][4], av[2][4];
#pragma unroll
    for (int s = 0; s < 2; ++s)
#pragma unroll
        for (int i = 0; i < 4; ++i) {
            aq[s][i] = (f32x4){0.f, 0.f, 0.f, 0.f};
            ak[s][i] = (f32x4){0.f, 0.f, 0.f, 0.f};
            av[s][i] = (f32x4){0.f, 0.f, 0.f, 0.f};
        }

    const int r0    = rowTile * 128;
    const int a_row = t >> 1;            // 0..127
    const int a_col = (t & 1) * 16;      // 0 or 16
    const int b_row = t >> 2;            // 0..63 (d)
    const int b_col = (t & 3) * 8;       // 0..24 (k)

    for (int k0 = 0; k0 < DM; k0 += 32) {
        __syncthreads();
        *(bf16x8*)&As[a_row * 40 + a_col] =
            load8f(X, (size_t)(r0 + a_row) * DM + k0 + a_col);
        *(bf16x8*)&As[a_row * 40 + a_col + 8] =
            load8f(X, (size_t)(r0 + a_row) * DM + k0 + a_col + 8);
        *(bf16x8*)&Bq[b_row * 40 + b_col] =
            *(const bf16x8*)&Wqt[woff + (size_t)b_row * DM + k0 + b_col];
        *(bf16x8*)&Bk[b_row * 40 + b_col] =
            *(const bf16x8*)&Wkt[woff + (size_t)b_row * DM + k0 + b_col];
        *(bf16x8*)&Bv[b_row * 40 + b_col] =
            *(const bf16x8*)&Wvt[woff + (size_t)b_row * DM + k0 + b_col];
        __syncthreads();

        bf16x8 a0 = *(const bf16x8*)&As[(wave * 16 + l15) * 40 + quad * 8];
        bf16x8 a1 = *(const bf16x8*)&As[(64 + wave * 16 + l15) * 40 + quad * 8];
#pragma unroll
        for (int ct = 0; ct < 4; ++ct) {
            bf16x8 bq = *(const bf16x8*)&Bq[(ct * 16 + l15) * 40 + quad * 8];
            aq[0][ct] = __builtin_amdgcn_mfma_f32_16x16x32_bf16(a0, bq, aq[0][ct], 0, 0, 0);
            aq[1][ct] = __builtin_amdgcn_mfma_f32_16x16x32_bf16(a1, bq, aq[1][ct], 0, 0, 0);
            bf16x8 bk = *(const bf16x8*)&Bk[(ct * 16 + l15) * 40 + quad * 8];
            ak[0][ct] = __builtin_amdgcn_mfma_f32_16x16x32_bf16(a0, bk, ak[0][ct], 0, 0, 0);
            ak[1][ct] = __builtin_amdgcn_mfma_f32_16x16x32_bf16(a1, bk, ak[1][ct], 0, 0, 0);
            bf16x8 bv = *(const bf16x8*)&Bv[(ct * 16 + l15) * 40 + quad * 8];
            av[0][ct] = __builtin_amdgcn_mfma_f32_16x16x32_bf16(a0, bv, av[0][ct], 0, 0, 0);
            av[1][ct] = __builtin_amdgcn_mfma_f32_16x16x32_bf16(a1, bv, av[1][ct], 0, 0, 0);
        }
    }

#pragma unroll
    for (int st = 0; st < 2; ++st) {
        const int rbase = r0 + st * 64 + wave * 16 + quad * 4;
        const int b = rbase >> 11;
        const int s = rbase & (SEQ - 1);
        const size_t bh = (size_t)(b * NH + h);
#pragma unroll
        for (int ct = 0; ct < 4; ++ct) {
            const int d = ct * 16 + l15;
#pragma unroll
            for (int reg = 0; reg < 4; ++reg) {
                Qo[(bh * SEQ + s + reg) * DH + d] = (__bf16)(aq[st][ct][reg] * QSCALE);
                Ko[(bh * SEQ + s + reg) * DH + d] = (__bf16)ak[st][ct][reg];
            }
            bf16x4 vv;
            vv[0] = (__bf16)av[st][ct][0]; vv[1] = (__bf16)av[st][ct][1];
            vv[2] = (__bf16)av[st][ct][2]; vv[3] = (__bf16)av[st][ct][3];
            *(bf16x4*)&Vto[(bh * DH + d) * SEQ + s] = vv;
        }
    }
}

// ---------------------------------------------------------------------------
// Kernel 2: causal flash attention. grid=(32 q-tiles, B*H=64), block=256.
// Q fragments register-resident (read from LDS once); Ps reuses the Q LDS
// region (rows are wave-private). exp2-domain softmax (Q pre-scaled).
// Next K/V tile's global loads issued before the compute phase.
// ---------------------------------------------------------------------------
__global__ __launch_bounds__(256)
void attn_kernel(const __bf16* __restrict__ Q,
                 const __bf16* __restrict__ K,
                 const __bf16* __restrict__ Vt,
                 __bf16* __restrict__ Cat)
{
    const int qt = 31 - blockIdx.x;   // heavy blocks first
    const int bh = blockIdx.y;        // 0..63
    const int b  = bh >> 4;
    const int h  = bh & 15;

    const __bf16* Qg  = Q  + (size_t)bh * SEQ * DH;
    const __bf16* Kg  = K  + (size_t)bh * SEQ * DH;
    const __bf16* Vtg = Vt + (size_t)bh * DH * SEQ;

    __shared__ __align__(16) __bf16 QPs[64 * 72];  // Q staging, then P
    __shared__ __align__(16) __bf16 Ks [64 * 72];
    __shared__ __align__(16) __bf16 Vs [64 * 72];  // V^T tile: [d][kv]

    const int t    = threadIdx.x;
    const int wave = t >> 6;
    const int lane = t & 63;
    const int l15  = lane & 15;
    const int quad = lane >> 4;

    const int q0 = qt * 64;

    // staging geometry (shared by Q/K/V tiles)
    const int srow0 = t >> 3;             // i=0 rows 0..31
    const int scol  = (t & 7) * 8;

    // stage Q tile, then pull this wave's A-fragments into registers
#pragma unroll
    for (int i = 0; i < 2; ++i) {
        int row = srow0 + i * 32;
        *(bf16x8*)&QPs[row * 72 + scol] =
            *(const bf16x8*)&Qg[(size_t)(q0 + row) * DH + scol];
    }
    __syncthreads();
    bf16x8 qf0 = *(const bf16x8*)&QPs[(wave * 16 + l15) * 72 + quad * 8];
    bf16x8 qf1 = *(const bf16x8*)&QPs[(wave * 16 + l15) * 72 + 32 + quad * 8];

    bf16x8 ones;
#pragma unroll
    for (int j = 0; j < 8; ++j) ones[j] = (__bf16)1.0f;

    float m_i[4];
    f32x4 o[4], ol;
#pragma unroll
    for (int r = 0; r < 4; ++r) m_i[r] = -INFINITY;
#pragma unroll
    for (int ct = 0; ct < 4; ++ct) o[ct] = (f32x4){0.f, 0.f, 0.f, 0.f};
    ol = (f32x4){0.f, 0.f, 0.f, 0.f};

    // prologue: issue kt=0 loads
    bf16x8 kreg[2], vreg[2];
#pragma unroll
    for (int i = 0; i < 2; ++i) {
        int row = srow0 + i * 32;
        kreg[i] = *(const bf16x8*)&Kg[(size_t)row * DH + scol];
        vreg[i] = *(const bf16x8*)&Vtg[(size_t)row * SEQ + scol];
    }

    for (int kt = 0; kt <= qt; ++kt) {
        __syncthreads();   // prior Ks/Vs readers drained
#pragma unroll
        for (int i = 0; i < 2; ++i) {
            int row = srow0 + i * 32;
            *(bf16x8*)&Ks[row * 72 + scol] = kreg[i];
            *(bf16x8*)&Vs[row * 72 + scol] = vreg[i];
        }
        __syncthreads();

        // issue next tile's loads (clamped; overlap with compute below)
        {
            const int kvn = (kt < qt ? kt + 1 : kt) * 64;
#pragma unroll
            for (int i = 0; i < 2; ++i) {
                int row = srow0 + i * 32;
                kreg[i] = *(const bf16x8*)&Kg[(size_t)(kvn + row) * DH + scol];
                vreg[i] = *(const bf16x8*)&Vtg[(size_t)row * SEQ + kvn + scol];
            }
        }

        // S = Q K^T (log2-domain: Q pre-scaled by 0.125*log2e)
        f32x4 sc[4];
#pragma unroll
        for (int ct = 0; ct < 4; ++ct) sc[ct] = (f32x4){0.f, 0.f, 0.f, 0.f};
#pragma unroll
        for (int ct = 0; ct < 4; ++ct) {
            bf16x8 b0 = *(const bf16x8*)&Ks[(ct * 16 + l15) * 72 + quad * 8];
            sc[ct] = __builtin_amdgcn_mfma_f32_16x16x32_bf16(qf0, b0, sc[ct], 0, 0, 0);
            bf16x8 b1 = *(const bf16x8*)&Ks[(ct * 16 + l15) * 72 + 32 + quad * 8];
            sc[ct] = __builtin_amdgcn_mfma_f32_16x16x32_bf16(qf1, b1, sc[ct], 0, 0, 0);
        }

        if (kt == qt) {     // causal mask, diagonal tile only
#pragma unroll
            for (int ct = 0; ct < 4; ++ct)
#pragma unroll
                for (int r = 0; r < 4; ++r) {
                    int qrow = wave * 16 + quad * 4 + r;
                    int kcol = ct * 16 + l15;
                    if (kcol > qrow) sc[ct][r] = -INFINITY;
                }
        }

        // online max + exp2; row sum via ones-MFMA
#pragma unroll
        for (int r = 0; r < 4; ++r) {
            float mx = fmaxf(fmaxf(sc[0][r], sc[1][r]), fmaxf(sc[2][r], sc[3][r]));
#pragma unroll
            for (int off = 1; off < 16; off <<= 1)
                mx = fmaxf(mx, __shfl_xor(mx, off, 64));
            float mnew  = fmaxf(m_i[r], mx);
            float alpha = exp2f(m_i[r] - mnew);
            m_i[r] = mnew;
#pragma unroll
            for (int ct = 0; ct < 4; ++ct) {
                sc[ct][r] = exp2f(sc[ct][r] - mnew);
                o[ct][r] *= alpha;
            }
            ol[r] *= alpha;
        }

        // P -> LDS (rows 16*wave..+15 are wave-private; no barrier needed)
#pragma unroll
        for (int ct = 0; ct < 4; ++ct)
#pragma unroll
            for (int r = 0; r < 4; ++r)
                QPs[(wave * 16 + quad * 4 + r) * 72 + ct * 16 + l15] = (__bf16)sc[ct][r];

        // O += P @ V ; ol += P @ 1
#pragma unroll
        for (int ks = 0; ks < 2; ++ks) {
            bf16x8 a = *(const bf16x8*)&QPs[(wave * 16 + l15) * 72 + ks * 32 + quad * 8];
#pragma unroll
            for (int ct = 0; ct < 4; ++ct) {
                bf16x8 bb = *(const bf16x8*)&Vs[(ct * 16 + l15) * 72 + ks * 32 + quad * 8];
                o[ct] = __builtin_amdgcn_mfma_f32_16x16x32_bf16(a, bb, o[ct], 0, 0, 0);
            }
            ol = __builtin_amdgcn_mfma_f32_16x16x32_bf16(a, ones, ol, 0, 0, 0);
        }
    }

    // epilogue
#pragma unroll
    for (int ct = 0; ct < 4; ++ct)
#pragma unroll
        for (int r = 0; r < 4; ++r) {
            int row = wave * 16 + quad * 4 + r;
            int s   = q0 + row;
            float val = o[ct][r] / ol[r];
            Cat[((size_t)(b * SEQ + s)) * DM + h * DH + ct * 16 + l15] = (__bf16)val;
        }
}

// ---------------------------------------------------------------------------
// Kernel 3: output projection. grid=(64 row tiles of 128, 8 col tiles of 128).
// out[8192x1024] = Cat(bf16) @ Wout, fp32 out. 16 MFMA per barrier-pair.
// ---------------------------------------------------------------------------
__global__ __launch_bounds__(256)
void oproj_kernel(const __bf16* __restrict__ A,
                  const __bf16* __restrict__ Wot,
                  float* __restrict__ C)
{
    const int rowTile = blockIdx.x;  // 0..63
    const int colTile = blockIdx.y;  // 0..7
    const int r0 = rowTile * 128;
    const int n0 = colTile * 128;

    __shared__ __align__(16) __bf16 As[128 * 40];
    __shared__ __align__(16) __bf16 Bs[128 * 40];

    const int t    = threadIdx.x;
    const int wave = t >> 6;
    const int lane = t & 63;
    const int l15  = lane & 15;
    const int quad = lane >> 4;

    f32x4 acc[2][8];
#pragma unroll
    for (int s = 0; s < 2; ++s)
#pragma unroll
        for (int i = 0; i < 8; ++i) acc[s][i] = (f32x4){0.f, 0.f, 0.f, 0.f};

    const int a_row = t >> 1;            // 0..127
    const int a_col = (t & 1) * 16;      // 0 or 16

    for (int k0 = 0; k0 < DM; k0 += 32) {
        __syncthreads();
        *(bf16x8*)&As[a_row * 40 + a_col] =
            *(const bf16x8*)&A[(size_t)(r0 + a_row) * DM + k0 + a_col];
        *(bf16x8*)&As[a_row * 40 + a_col + 8] =
            *(const bf16x8*)&A[(size_t)(r0 + a_row) * DM + k0 + a_col + 8];
        *(bf16x8*)&Bs[a_row * 40 + a_col] =
            *(const bf16x8*)&Wot[(size_t)(n0 + a_row) * DM + k0 + a_col];
        *(bf16x8*)&Bs[a_row * 40 + a_col + 8] =
            *(const bf16x8*)&Wot[(size_t)(n0 + a_row) * DM + k0 + a_col + 8];
        __syncthreads();

        bf16x8 a0 = *(const bf16x8*)&As[(wave * 16 + l15) * 40 + quad * 8];
        bf16x8 a1 = *(const bf16x8*)&As[(64 + wave * 16 + l15) * 40 + quad * 8];
#pragma unroll
        for (int ct = 0; ct < 8; ++ct) {
            bf16x8 bb = *(const bf16x8*)&Bs[(ct * 16 + l15) * 40 + quad * 8];
            acc[0][ct] = __builtin_amdgcn_mfma_f32_16x16x32_bf16(a0, bb, acc[0][ct], 0, 0, 0);
            acc[1][ct] = __builtin_amdgcn_mfma_f32_16x16x32_bf16(a1, bb, acc[1][ct], 0, 0, 0);
        }
    }

#pragma unroll
    for (int st = 0; st < 2; ++st)
#pragma unroll
        for (int ct = 0; ct < 8; ++ct)
#pragma unroll
            for (int reg = 0; reg < 4; ++reg) {
                int r = r0 + st * 64 + wave * 16 + quad * 4 + reg;
                int n = n0 + ct * 16 + l15;
                C[(size_t)r * DM + n] = acc[st][ct][reg];
            }
}

// ---------------------------------------------------------------------------
extern "C" void kernel_launch(void* const* d_in, const int* in_sizes, int n_in,
                              void* d_out, int out_size, void* d_ws, size_t ws_size,
                              hipStream_t stream)
{
    (void)in_sizes; (void)n_in; (void)out_size; (void)ws_size;
    const float* X  = (const float*)d_in[0];
    const float* Wq = (const float*)d_in[1];
    const float* Wk = (const float*)d_in[2];
    const float* Wv = (const float*)d_in[3];
    const float* Wo = (const float*)d_in[4];
    float* out = (float*)d_out;

    char* ws = (char*)d_ws;
    const size_t wqkv_b = (size_t)NH * DM * DH * sizeof(__bf16);          // 2 MiB
    const size_t wo_b   = (size_t)DM * DM * sizeof(__bf16);               // 2 MiB
    const size_t big_b  = (size_t)BATCH * NH * SEQ * DH * sizeof(__bf16); // 16 MiB
    __bf16* Wqt = (__bf16*)(ws);
    __bf16* Wkt = (__bf16*)(ws + wqkv_b);
    __bf16* Wvt = (__bf16*)(ws + 2 * wqkv_b);
    __bf16* Wot = (__bf16*)(ws + 3 * wqkv_b);
    __bf16* Qb  = (__bf16*)(ws + 3 * wqkv_b + wo_b);
    __bf16* Kb  = (__bf16*)(ws + 3 * wqkv_b + wo_b + big_b);
    __bf16* Vtb = (__bf16*)(ws + 3 * wqkv_b + wo_b + 2 * big_b);
    __bf16* Cat = (__bf16*)(ws + 3 * wqkv_b + wo_b + 3 * big_b);

    wtrans_kernel<<<dim3(16, 1, 16), 256, 0, stream>>>(Wq, Wqt, DM, DH);
    wtrans_kernel<<<dim3(16, 1, 16), 256, 0, stream>>>(Wk, Wkt, DM, DH);
    wtrans_kernel<<<dim3(16, 1, 16), 256, 0, stream>>>(Wv, Wvt, DM, DH);
    wtrans_kernel<<<dim3(16, 16, 1), 256, 0, stream>>>(Wo, Wot, DM, DM);
    qkv_kernel<<<dim3(64, 16), 256, 0, stream>>>(X, Wqt, Wkt, Wvt, Qb, Kb, Vtb);
    attn_kernel<<<dim3(32, 64), 256, 0, stream>>>(Qb, Kb, Vtb, Cat);
    oproj_kernel<<<dim3(64, 8), 256, 0, stream>>>(Cat, Wot, out);
}